// Round 2
// baseline (697.500 us; speedup 1.0000x reference)
//
#include <hip/hip_runtime.h>
#include <hip/hip_bf16.h>

#define NEG_BIG (-3.402823466e38f)

// ---------------- CSR build ----------------
__global__ void deg_kernel(const int* __restrict__ dst, int* __restrict__ deg, int E) {
    int e = blockIdx.x * blockDim.x + threadIdx.x;
    if (e < E) atomicAdd(&deg[dst[e]], 1);
}

__global__ void scan_kernel(const int* __restrict__ deg, int* __restrict__ off,
                            int* __restrict__ cursor, int n) {
    __shared__ int sh[1024];
    int tid = threadIdx.x;
    int chunk = (n + 1023) >> 10;
    int s0 = tid * chunk, s1 = min(s0 + chunk, n);
    int sum = 0;
    for (int i = s0; i < s1; ++i) sum += deg[i];
    sh[tid] = sum;
    __syncthreads();
    for (int d = 1; d < 1024; d <<= 1) {
        int t = 0;
        if (tid >= d) t = sh[tid - d];
        __syncthreads();
        sh[tid] += t;
        __syncthreads();
    }
    int run = sh[tid] - sum;  // exclusive prefix
    for (int i = s0; i < s1; ++i) {
        off[i] = run; cursor[i] = run;
        run += deg[i];
    }
    if (tid == 1023) off[n] = sh[1023];
}

__global__ void scatter_kernel(const int* __restrict__ src, const int* __restrict__ dst,
                               int* __restrict__ cursor, int* __restrict__ srcs, int E) {
    int e = blockIdx.x * blockDim.x + threadIdx.x;
    if (e < E) {
        int p = atomicAdd(&cursor[dst[e]], 1);
        srcs[p] = src[e];
    }
}

// ---------------- linear projections ----------------
// x (n,3) -> q,k,v (n,64). block 256 = 4 nodes x 64 dims
__global__ void lin1_kernel(const float* __restrict__ x,
                            const float* __restrict__ Wq, const float* __restrict__ bq,
                            const float* __restrict__ Wk, const float* __restrict__ bk,
                            const float* __restrict__ Wv, const float* __restrict__ bv,
                            float* __restrict__ q, float* __restrict__ k, float* __restrict__ v,
                            int n) {
    int i = blockIdx.x * 4 + (threadIdx.x >> 6);
    int c = threadIdx.x & 63;
    if (i >= n) return;
    float x0 = x[i * 3], x1 = x[i * 3 + 1], x2 = x[i * 3 + 2];
    q[i * 64 + c] = bq[c] + x0 * Wq[c] + x1 * Wq[64 + c] + x2 * Wq[128 + c];
    k[i * 64 + c] = bk[c] + x0 * Wk[c] + x1 * Wk[64 + c] + x2 * Wk[128 + c];
    v[i * 64 + c] = bv[c] + x0 * Wv[c] + x1 * Wv[64 + c] + x2 * Wv[128 + c];
}

// h1 (n,64) -> q,k,v (n,128). block 256 = 2 nodes x 128 dims
__global__ void lin2_kernel(const float* __restrict__ h1,
                            const float* __restrict__ Wq, const float* __restrict__ bq,
                            const float* __restrict__ Wk, const float* __restrict__ bk,
                            const float* __restrict__ Wv, const float* __restrict__ bv,
                            float* __restrict__ q, float* __restrict__ k, float* __restrict__ v,
                            int n) {
    __shared__ float sh[2][64];
    int node0 = blockIdx.x * 2;
    int r = threadIdx.x >> 7;
    int c = threadIdx.x & 127;
    if (threadIdx.x < 128) {
        int rr = threadIdx.x >> 6, kk = threadIdx.x & 63;
        int ii = node0 + rr;
        sh[rr][kk] = (ii < n) ? h1[ii * 64 + kk] : 0.f;
    }
    __syncthreads();
    int i = node0 + r;
    if (i >= n) return;
    float aq = bq[c], ak = bk[c], av = bv[c];
    for (int kk = 0; kk < 64; ++kk) {
        float hv = sh[r][kk];
        aq += hv * Wq[kk * 128 + c];
        ak += hv * Wk[kk * 128 + c];
        av += hv * Wv[kk * 128 + c];
    }
    q[i * 128 + c] = aq;
    k[i * 128 + c] = ak;
    v[i * 128 + c] = av;
}

// ---------------- fused attention (segment softmax, online) ----------------
// One 64-lane wave per destination node. C = H*d total channels.
// C==64 : H=2,d=32; lane l -> head l>>5, dim l&31 (reduce within 32-half)
// C==128: H=2,d=64; lane l -> (head0,dim l) and (head1,dim l) (full-wave reduce)
// Epilogue fuses skip (xin @ Ws + bs) and ReLU.
template <int C, int IN>
__global__ void attn_kernel(const float* __restrict__ q, const float* __restrict__ k,
                            const float* __restrict__ v,
                            const float* __restrict__ xin, const float* __restrict__ Ws,
                            const float* __restrict__ bs,
                            const int* __restrict__ off, const int* __restrict__ srcs,
                            float* __restrict__ out, int n, float scale) {
    int i = blockIdx.x * (blockDim.x >> 6) + (threadIdx.x >> 6);
    int lane = threadIdx.x & 63;
    if (i >= n) return;
    int e0 = off[i], e1 = off[i + 1];
    if constexpr (C == 64) {
        float qv = q[i * 64 + lane];
        float m = NEG_BIG, denom = 0.f, acc = 0.f;
        for (int e = e0; e < e1; ++e) {
            int j = srcs[e];
            float t = qv * k[j * 64 + lane];
            t += __shfl_xor(t, 1);
            t += __shfl_xor(t, 2);
            t += __shfl_xor(t, 4);
            t += __shfl_xor(t, 8);
            t += __shfl_xor(t, 16);
            float s = t * scale;
            float mn = fmaxf(m, s);
            float corr = __expf(m - mn);
            float p = __expf(s - mn);
            denom = denom * corr + p;
            acc = acc * corr + p * v[j * 64 + lane];
            m = mn;
        }
        float sk = bs[lane];
#pragma unroll
        for (int kk = 0; kk < IN; ++kk) sk += xin[i * IN + kk] * Ws[kk * 64 + lane];
        float o = acc / fmaxf(denom, 1e-16f) + sk;
        out[i * 64 + lane] = fmaxf(o, 0.f);
    } else {
        float qv0 = q[i * 128 + lane], qv1 = q[i * 128 + 64 + lane];
        float m0 = NEG_BIG, m1 = NEG_BIG, d0 = 0.f, d1 = 0.f, a0 = 0.f, a1 = 0.f;
        for (int e = e0; e < e1; ++e) {
            int j = srcs[e];
            float t0 = qv0 * k[j * 128 + lane];
            float t1 = qv1 * k[j * 128 + 64 + lane];
#pragma unroll
            for (int msk = 1; msk <= 32; msk <<= 1) {
                t0 += __shfl_xor(t0, msk);
                t1 += __shfl_xor(t1, msk);
            }
            float s0 = t0 * scale, s1 = t1 * scale;
            float mn0 = fmaxf(m0, s0), mn1 = fmaxf(m1, s1);
            float c0 = __expf(m0 - mn0), c1 = __expf(m1 - mn1);
            float p0 = __expf(s0 - mn0), p1 = __expf(s1 - mn1);
            d0 = d0 * c0 + p0; d1 = d1 * c1 + p1;
            a0 = a0 * c0 + p0 * v[j * 128 + lane];
            a1 = a1 * c1 + p1 * v[j * 128 + 64 + lane];
            m0 = mn0; m1 = mn1;
        }
        float sk0 = bs[lane], sk1 = bs[64 + lane];
        for (int kk = 0; kk < IN; ++kk) {
            float hv = xin[i * IN + kk];
            sk0 += hv * Ws[kk * 128 + lane];
            sk1 += hv * Ws[kk * 128 + 64 + lane];
        }
        out[i * 128 + lane] = fmaxf(a0 / fmaxf(d0, 1e-16f) + sk0, 0.f);
        out[i * 128 + 64 + lane] = fmaxf(a1 / fmaxf(d1, 1e-16f) + sk1, 0.f);
    }
}

// ---------------- global max pool (h2 >= 0 post-ReLU -> bitwise uint max works) ----
__global__ void pool_kernel(const float* __restrict__ h2, const int* __restrict__ batch,
                            unsigned* __restrict__ p, int n) {
    int idx = blockIdx.x * blockDim.x + threadIdx.x;
    if (idx >= n * 128) return;
    int i = idx >> 7;
    float val = h2[idx];
    int g = batch[i];
    atomicMax(&p[g * 128 + (idx & 127)], __float_as_uint(val));
}

// ---------------- MLP head: out0 = relu(relu(p@W1+b1)@W2+b2)@W3+b3 ; out1 = x_latent
__global__ void head_kernel(const unsigned* __restrict__ pbits,
                            const float* __restrict__ W1, const float* __restrict__ b1,
                            const float* __restrict__ W2, const float* __restrict__ b2,
                            const float* __restrict__ W3, const float* __restrict__ b3,
                            float* __restrict__ out, int G) {
    int g = blockIdx.x;
    int t = threadIdx.x;  // 128 threads
    __shared__ float ps[128], xl[32], y[128];
    ps[t] = __uint_as_float(pbits[g * 128 + t]);
    __syncthreads();
    if (t < 32) {
        float a = b1[t];
        for (int k = 0; k < 128; ++k) a += ps[k] * W1[k * 32 + t];
        a = fmaxf(a, 0.f);
        xl[t] = a;
        out[G * 40 + g * 32 + t] = a;  // x_latent block after out0 block
    }
    __syncthreads();
    {
        float a = b2[t];
        for (int k = 0; k < 32; ++k) a += xl[k] * W2[k * 128 + t];
        y[t] = fmaxf(a, 0.f);
    }
    __syncthreads();
    if (t < 40) {
        float a = b3[t];
        // W3 shape (128, 40): W3[k][t] = W3[k*40 + t]
        for (int k = 0; k < 128; ++k) a += y[k] * W3[k * 40 + t];
        out[g * 40 + t] = a;
    }
}

extern "C" void kernel_launch(void* const* d_in, const int* in_sizes, int n_in,
                              void* d_out, int out_size, void* d_ws, size_t ws_size,
                              hipStream_t stream) {
    const float* x = (const float*)d_in[0];
    const int* eidx = (const int*)d_in[1];
    const int* batch = (const int*)d_in[2];
    const float *Wq1 = (const float*)d_in[3], *bq1 = (const float*)d_in[4];
    const float *Wk1 = (const float*)d_in[5], *bk1 = (const float*)d_in[6];
    const float *Wv1 = (const float*)d_in[7], *bv1 = (const float*)d_in[8];
    const float *Ws1 = (const float*)d_in[9], *bs1 = (const float*)d_in[10];
    const float *Wq2 = (const float*)d_in[11], *bq2 = (const float*)d_in[12];
    const float *Wk2 = (const float*)d_in[13], *bk2 = (const float*)d_in[14];
    const float *Wv2 = (const float*)d_in[15], *bv2 = (const float*)d_in[16];
    const float *Ws2 = (const float*)d_in[17], *bs2 = (const float*)d_in[18];
    const float *W1 = (const float*)d_in[19], *b1 = (const float*)d_in[20];
    const float *W2 = (const float*)d_in[21], *b2 = (const float*)d_in[22];
    const float *W3 = (const float*)d_in[23], *b3 = (const float*)d_in[24];

    const int N = in_sizes[0] / 3;
    const int E = in_sizes[1] / 2;
    const int G = out_size / 72;  // 40 + 32 per graph
    const int* esrc = eidx;
    const int* edst = eidx + E;

    // workspace carve-out
    char* w = (char*)d_ws;
    size_t o = 0;
    auto alloc = [&](size_t bytes) {
        void* p = w + o;
        o = (o + bytes + 255) & ~(size_t)255;
        return p;
    };
    float* bufQ = (float*)alloc((size_t)N * 128 * 4);
    float* bufK = (float*)alloc((size_t)N * 128 * 4);
    float* bufV = (float*)alloc((size_t)N * 128 * 4);
    float* h1 = (float*)alloc((size_t)N * 64 * 4);
    float* h2 = (float*)alloc((size_t)N * 128 * 4);
    int* deg = (int*)alloc((size_t)N * 4);
    int* off = (int*)alloc((size_t)(N + 1) * 4);
    int* cursor = (int*)alloc((size_t)N * 4);
    int* srcs = (int*)alloc((size_t)E * 4);
    unsigned* pool = (unsigned*)alloc((size_t)G * 128 * 4);
    (void)ws_size;

    // CSR by destination
    hipMemsetAsync(deg, 0, (size_t)N * 4, stream);
    deg_kernel<<<(E + 255) / 256, 256, 0, stream>>>(edst, deg, E);
    scan_kernel<<<1, 1024, 0, stream>>>(deg, off, cursor, N);
    scatter_kernel<<<(E + 255) / 256, 256, 0, stream>>>(esrc, edst, cursor, srcs, E);

    // layer 1
    lin1_kernel<<<(N + 3) / 4, 256, 0, stream>>>(x, Wq1, bq1, Wk1, bk1, Wv1, bv1,
                                                 bufQ, bufK, bufV, N);
    attn_kernel<64, 3><<<(N + 3) / 4, 256, 0, stream>>>(bufQ, bufK, bufV, x, Ws1, bs1,
                                                        off, srcs, h1, N, 0.1767766953f);
    // layer 2
    lin2_kernel<<<(N + 1) / 2, 256, 0, stream>>>(h1, Wq2, bq2, Wk2, bk2, Wv2, bv2,
                                                 bufQ, bufK, bufV, N);
    attn_kernel<128, 64><<<(N + 3) / 4, 256, 0, stream>>>(bufQ, bufK, bufV, h1, Ws2, bs2,
                                                          off, srcs, h2, N, 0.125f);

    // pool + head
    hipMemsetAsync(pool, 0, (size_t)G * 128 * 4, stream);
    pool_kernel<<<((size_t)N * 128 + 255) / 256, 256, 0, stream>>>(h2, batch, pool, N);
    head_kernel<<<G, 128, 0, stream>>>(pool, W1, b1, W2, b2, W3, b3, (float*)d_out, G);
}